// Round 15
// baseline (173.539 us; speedup 1.0000x reference)
//
#include <hip/hip_runtime.h>
#include <math.h>

#define NEG 0.2f
#define BCAP 10240            // per-bucket slab capacity (mean 8163, +23 sigma)

typedef __attribute__((ext_vector_type(8))) short bf16x8;
typedef __attribute__((ext_vector_type(4))) float f32x4;

__device__ __forceinline__ unsigned short f2bf(float f) {
    unsigned u = __float_as_uint(f);
    u += 0x7fffu + ((u >> 16) & 1u);
    return (unsigned short)(u >> 16);
}
__device__ __forceinline__ unsigned pkbf(float a, float b) {
    return (unsigned)f2bf(a) | ((unsigned)f2bf(b) << 16);
}
__device__ __forceinline__ float blo(unsigned v) { return __uint_as_float(v << 16); }
__device__ __forceinline__ float bhi(unsigned v) { return __uint_as_float(v & 0xffff0000u); }
__device__ __forceinline__ float lrexp(float v) {
    v = v > 0.f ? v : NEG * v;
    return __expf(v);
}

// ---------------------------------------------------------------------------
// K0: build wt [272][128] bf16 transposed weights (lin | skip | w_as | w_ad)
// + zero the small scratch (esrc pad + fill).
// ---------------------------------------------------------------------------
__global__ __launch_bounds__(256) void k0_wt(
    const float* __restrict__ lin_w, const float* __restrict__ skip_w,
    const float* __restrict__ att_src, const float* __restrict__ att_dst,
    unsigned short* __restrict__ wt, int* __restrict__ zbase)
{
    int idx = blockIdx.x * 256 + threadIdx.x;   // 0..34815
    if (blockIdx.x == 0) {
        for (int z = threadIdx.x; z < 264; z += 256) zbase[z] = 0;
    }
    int c = idx >> 7, k = idx & 127;
    float v;
    if (c < 128) {
        v = lin_w[k * 128 + c];
    } else if (c < 256) {
        v = skip_w[k * 128 + (c - 128)];
    } else {
        int hh = c & 7;
        const float* att = (c & 8) ? att_dst : att_src;
        const float* wrow = lin_w + k * 128 + hh * 16;
        float s = 0.f;
#pragma unroll
        for (int j = 0; j < 16; ++j) s += wrow[j] * att[hh * 16 + j];
        v = s;
    }
    wt[c * 128 + k] = f2bf(v);
}

// ---------------------------------------------------------------------------
// K1F: [blocks 0..nbin) = edge binning; [nbin..) = persistent B-stationary
// MFMA GEMM (unchanged from R14).
// ---------------------------------------------------------------------------
__global__ __launch_bounds__(512, 2) void k1f(
    const float* __restrict__ x, const unsigned short* __restrict__ wt,
    const float* __restrict__ gat_bias, const float* __restrict__ skip_b,
    const int* __restrict__ ei,
    unsigned short* __restrict__ xh_bf, float* __restrict__ a_src,
    float* __restrict__ a_dst, float* __restrict__ out,
    int* __restrict__ fill, unsigned* __restrict__ binned,
    int nrows, int E, int nbin, int ntiles, int G)
{
    __shared__ int s1[256];
    __shared__ int s2[256];
    const int t = threadIdx.x;
    const int bid = blockIdx.x;

    if (bid < nbin) {                 // ---- binning role ----
        if (t < 256) s1[t] = 0;
        __syncthreads();
        int eb = bid * 8192;
        int srcv[16], dstv[16], rkv[16];
#pragma unroll
        for (int u = 0; u < 16; ++u) {
            int e = eb + u * 512 + t;
            srcv[u] = 0; dstv[u] = -1; rkv[u] = 0;
            if (e < E) {
                srcv[u] = ei[e];
                dstv[u] = ei[E + e];
                rkv[u] = atomicAdd(&s1[dstv[u] >> 9], 1);
            }
        }
        __syncthreads();
        if (t < 256) {
            int hc = s1[t];
            s2[t] = t * BCAP + (hc ? atomicAdd(&fill[t], hc) : 0);
        }
        __syncthreads();
#pragma unroll
        for (int u = 0; u < 16; ++u) {
            if (dstv[u] >= 0) {
                int b = dstv[u] >> 9;
                binned[s2[b] + rkv[u]] =
                    ((unsigned)(dstv[u] & 511) << 17) | (unsigned)srcv[u];
            }
        }
        return;
    }

    // ---- persistent GEMM role, B-stationary ----
    const int w = t >> 6, l = t & 63, r = l & 15, half = l >> 4;
    const int cb = w >> 2;

    bf16x8 Bf[4][8];                 // [ks][cf]
#pragma unroll
    for (int ks = 0; ks < 4; ++ks)
#pragma unroll
        for (int cf = 0; cf < 8; ++cf) {
            const int c = cb * 128 + cf * 16 + r;
            Bf[ks][cf] = *(const bf16x8*)(wt + c * 128 + ks * 32 + half * 8);
        }
    bf16x8 bA[4];
    float4 gb[8];
    if (cb == 0) {
#pragma unroll
        for (int ks = 0; ks < 4; ++ks)
            bA[ks] = *(const bf16x8*)(wt + (256 + r) * 128 + ks * 32 + half * 8);
    } else {
#pragma unroll
        for (int cf = 0; cf < 8; ++cf) {
            const int c0 = cf * 16 + half * 4;
            float4 g = *(const float4*)(gat_bias + c0);
            float4 sb = *(const float4*)(skip_b + c0);
            gb[cf] = make_float4(g.x + sb.x, g.y + sb.y, g.z + sb.z, g.w + sb.w);
        }
    }

    for (int tile = (bid - nbin); tile < ntiles; tile += G) {
        const int row0 = tile * 64 + (w & 3) * 16;
        const int row = row0 + r;
        const bool rowok = row < nrows;
        const float* xrow = x + (size_t)row * 128;

        bf16x8 aF[4];
#pragma unroll
        for (int ks = 0; ks < 4; ++ks) {
            float4 v0 = make_float4(0.f, 0.f, 0.f, 0.f), v1 = v0;
            if (rowok) {
                const float* gp = xrow + ks * 32 + half * 8;
                v0 = *(const float4*)gp;
                v1 = *(const float4*)(gp + 4);
            }
            bf16x8 a;
            a[0] = f2bf(v0.x); a[1] = f2bf(v0.y); a[2] = f2bf(v0.z); a[3] = f2bf(v0.w);
            a[4] = f2bf(v1.x); a[5] = f2bf(v1.y); a[6] = f2bf(v1.z); a[7] = f2bf(v1.w);
            aF[ks] = a;
        }

        f32x4 acc[8];
#pragma unroll
        for (int cf = 0; cf < 8; ++cf) acc[cf] = (f32x4){0.f, 0.f, 0.f, 0.f};
        f32x4 accA = (f32x4){0.f, 0.f, 0.f, 0.f};

#pragma unroll
        for (int ks = 0; ks < 4; ++ks) {
#pragma unroll
            for (int cf = 0; cf < 8; ++cf)
                acc[cf] = __builtin_amdgcn_mfma_f32_16x16x32_bf16(Bf[ks][cf], aF[ks], acc[cf], 0, 0, 0);
            if (cb == 0)
                accA = __builtin_amdgcn_mfma_f32_16x16x32_bf16(bA[ks], aF[ks], accA, 0, 0, 0);
        }

        if (rowok) {
            if (cb == 0) {
#pragma unroll
                for (int cf = 0; cf < 8; ++cf) {
                    uint2 pk;
                    pk.x = pkbf(acc[cf][0], acc[cf][1]);
                    pk.y = pkbf(acc[cf][2], acc[cf][3]);
                    *(uint2*)(xh_bf + (size_t)row * 128 + cf * 16 + half * 4) = pk;
                }
                float* adst_base = (half < 2) ? a_src : a_dst;
                *(float4*)(adst_base + (size_t)row * 8 + (half & 1) * 4) =
                    make_float4(accA[0], accA[1], accA[2], accA[3]);
            } else {
#pragma unroll
                for (int cf = 0; cf < 8; ++cf) {
                    const int c0 = cf * 16 + half * 4;
                    *(float4*)(out + (size_t)row * 128 + c0) =
                        make_float4(acc[cf][0] + gb[cf].x, acc[cf][1] + gb[cf].y,
                                    acc[cf][2] + gb[cf].z, acc[cf][3] + gb[cf].w);
                }
            }
        }
    }
}

// ---------------------------------------------------------------------------
// F3: one block per bucket (512 nodes). Single pass CSR build (unchanged).
// ---------------------------------------------------------------------------
__global__ __launch_bounds__(256) void f3(
    const unsigned* __restrict__ binned, const int* __restrict__ fill,
    int* __restrict__ rowptr, int* __restrict__ cntn,
    int* __restrict__ esrc, int N, int nb)
{
    __shared__ unsigned le[BCAP];    // 40 KB
    __shared__ int bs[256];
    __shared__ int h[512];
    __shared__ int sc[256];
    const int t = threadIdx.x;
    const int b = blockIdx.x;

    int c = (t < nb) ? fill[t] : 0;
    bs[t] = c;
    __syncthreads();
    for (int off = 1; off < 256; off <<= 1) {
        int a = (t >= off) ? bs[t - off] : 0;
        __syncthreads();
        bs[t] += a;
        __syncthreads();
    }
    const int cnt = fill[b];
    const int baseE = bs[b] - cnt;

    h[t] = 0; h[t + 256] = 0;
    __syncthreads();
    for (int e = t; e < cnt; e += 256) {
        unsigned p = binned[b * BCAP + e];
        le[e] = p;
        atomicAdd(&h[p >> 17], 1);
    }
    __syncthreads();
    int i0 = 2 * t, i1 = i0 + 1;
    int c0 = h[i0], c1 = h[i1], pv = c0 + c1;
    sc[t] = pv;
    __syncthreads();
    for (int off = 1; off < 256; off <<= 1) {
        int a = (t >= off) ? sc[t - off] : 0;
        __syncthreads();
        sc[t] += a;
        __syncthreads();
    }
    int ex = sc[t] - pv;
    int n0 = b * 512 + i0;
    if (n0 < N)     { rowptr[n0]     = baseE + ex;      cntn[n0]     = c0; }
    if (n0 + 1 < N) { rowptr[n0 + 1] = baseE + ex + c0; cntn[n0 + 1] = c1; }
    h[i0] = baseE + ex;
    h[i1] = baseE + ex + c0;
    __syncthreads();
    for (int e = t; e < cnt; e += 256) {
        unsigned p = le[e];
        int slot = atomicAdd(&h[p >> 17], 1);
        esrc[slot] = (int)(p & 0x1FFFFu);
    }
}

// ---------------------------------------------------------------------------
// K3 R15: edge-paired dwordx2 gathers. Lanes 0-31 carry 4 channels of EVEN
// edges, lanes 32-63 of ODD edges (8B/lane, 2 edges per wave instruction);
// 16-edge chunks double in-flight lines. exp-producer roles unchanged
// (h=lane>>3, u=lane&7). Final xor-swap-add combines halves; lower half
// does the float4 skip+ELU store.
// ---------------------------------------------------------------------------
__global__ __launch_bounds__(256) void k3_agg(
    const int* __restrict__ rowptr, const int* __restrict__ cntn,
    const int* __restrict__ esrc,
    const float* __restrict__ a_src, const float* __restrict__ a_dst,
    const uint2* __restrict__ xh64, float* __restrict__ out, int n)
{
    int i = blockIdx.x * 4 + (threadIdx.x >> 6);
    if (i >= n) return;
    const int lane = threadIdx.x & 63;
    const int h = lane >> 3, u = lane & 7;      // exp-producer role
    const int el = lane >> 5, sl = lane & 31;   // gather role: even/odd, slot
    const int hb = (sl >> 2) << 3;              // consumer head * 8

    const float adi = a_dst[(unsigned)i * 8 + h];
    // self loop: p0 for consumer head, accumulated by lower half only
    const float p00 = lrexp(a_src[(unsigned)i * 8 + (sl >> 2)]
                          + a_dst[(unsigned)i * 8 + (sl >> 2)]);
    uint2 gs = xh64[(unsigned)i * 32 + sl];
    float ax = 0.f, ay = 0.f, az = 0.f, aw = 0.f, den = 0.f;
    if (el == 0) {
        ax = p00 * blo(gs.x); ay = p00 * bhi(gs.x);
        az = p00 * blo(gs.y); aw = p00 * bhi(gs.y);
        den = p00;
    }

    const int kbeg = rowptr[i], kend = kbeg + cntn[i];
    const int kl = kend - 1;
    for (int k = kbeg; k < kend; k += 16) {
        // producers: edges k+u (pm0) and k+8+u (pm1), head h
        int ke0 = k + u, ke1 = k + 8 + u;
        int jm0 = esrc[min(ke0, kl)];
        int jm1 = esrc[min(ke1, kl)];
        float pm0 = (ke0 < kend) ? lrexp(a_src[(unsigned)jm0 * 8 + h] + adi) : 0.f;
        float pm1 = (ke1 < kend) ? lrexp(a_src[(unsigned)jm1 * 8 + h] + adi) : 0.f;

        // my 8 gather edges: e = 2q+el (chunk0) and 8+2q+el (chunk1)
        int j0 = esrc[min(k + 0 + el, kl)];
        int j1 = esrc[min(k + 2 + el, kl)];
        int j2 = esrc[min(k + 4 + el, kl)];
        int j3 = esrc[min(k + 6 + el, kl)];
        int j4 = esrc[min(k + 8 + el, kl)];
        int j5 = esrc[min(k + 10 + el, kl)];
        int j6 = esrc[min(k + 12 + el, kl)];
        int j7 = esrc[min(k + 14 + el, kl)];
        uint2 g0 = xh64[(unsigned)j0 * 32 + sl];
        uint2 g1 = xh64[(unsigned)j1 * 32 + sl];
        uint2 g2 = xh64[(unsigned)j2 * 32 + sl];
        uint2 g3 = xh64[(unsigned)j3 * 32 + sl];
        uint2 g4 = xh64[(unsigned)j4 * 32 + sl];
        uint2 g5 = xh64[(unsigned)j5 * 32 + sl];
        uint2 g6 = xh64[(unsigned)j6 * 32 + sl];
        uint2 g7 = xh64[(unsigned)j7 * 32 + sl];

        float p;
        p = __shfl(pm0, hb | (0 + el), 64);
        ax += p * blo(g0.x); ay += p * bhi(g0.x); az += p * blo(g0.y); aw += p * bhi(g0.y); den += p;
        p = __shfl(pm0, hb | (2 + el), 64);
        ax += p * blo(g1.x); ay += p * bhi(g1.x); az += p * blo(g1.y); aw += p * bhi(g1.y); den += p;
        p = __shfl(pm0, hb | (4 + el), 64);
        ax += p * blo(g2.x); ay += p * bhi(g2.x); az += p * blo(g2.y); aw += p * bhi(g2.y); den += p;
        p = __shfl(pm0, hb | (6 + el), 64);
        ax += p * blo(g3.x); ay += p * bhi(g3.x); az += p * blo(g3.y); aw += p * bhi(g3.y); den += p;
        p = __shfl(pm1, hb | (0 + el), 64);
        ax += p * blo(g4.x); ay += p * bhi(g4.x); az += p * blo(g4.y); aw += p * bhi(g4.y); den += p;
        p = __shfl(pm1, hb | (2 + el), 64);
        ax += p * blo(g5.x); ay += p * bhi(g5.x); az += p * blo(g5.y); aw += p * bhi(g5.y); den += p;
        p = __shfl(pm1, hb | (4 + el), 64);
        ax += p * blo(g6.x); ay += p * bhi(g6.x); az += p * blo(g6.y); aw += p * bhi(g6.y); den += p;
        p = __shfl(pm1, hb | (6 + el), 64);
        ax += p * blo(g7.x); ay += p * bhi(g7.x); az += p * blo(g7.y); aw += p * bhi(g7.y); den += p;
    }

    // combine even/odd halves
    ax += __shfl(ax, lane ^ 32, 64);
    ay += __shfl(ay, lane ^ 32, 64);
    az += __shfl(az, lane ^ 32, 64);
    aw += __shfl(aw, lane ^ 32, 64);
    den += __shfl(den, lane ^ 32, 64);

    if (el == 0) {
        float inv = 1.f / (den + 1e-16f);
        float4 o = *(float4*)(out + (unsigned)i * 128 + sl * 4);
        o.x += ax * inv; o.y += ay * inv; o.z += az * inv; o.w += aw * inv;
        o.x = o.x > 0.f ? o.x : __expf(o.x) - 1.f;
        o.y = o.y > 0.f ? o.y : __expf(o.y) - 1.f;
        o.z = o.z > 0.f ? o.z : __expf(o.z) - 1.f;
        o.w = o.w > 0.f ? o.w : __expf(o.w) - 1.f;
        *(float4*)(out + (unsigned)i * 128 + sl * 4) = o;
    }
}

extern "C" void kernel_launch(void* const* d_in, const int* in_sizes, int n_in,
                              void* d_out, int out_size, void* d_ws, size_t ws_size,
                              hipStream_t stream)
{
    const float* x        = (const float*)d_in[0];
    const int*   ei       = (const int*)d_in[1];
    const float* lin_w    = (const float*)d_in[2];
    const float* att_src  = (const float*)d_in[3];
    const float* att_dst  = (const float*)d_in[4];
    const float* gat_bias = (const float*)d_in[5];
    const float* skip_w   = (const float*)d_in[6];
    const float* skip_b   = (const float*)d_in[7];
    float* out = (float*)d_out;

    const int N = in_sizes[0] / 128;
    const int E = in_sizes[1] / 2;
    const int nb   = (N + 511) >> 9;           // buckets (196)
    const int nbin = (E + 8191) / 8192;        // bin blocks (196)
    const int ntiles = (N + 63) / 64;
    int G = 2 * 256 - nbin;
    if (G < 64) G = 64;
    if (G > ntiles) G = ntiles;

    float* ws   = (float*)d_ws;
    float* asrc = ws;                                   // N*8 f
    float* adst = asrc + (size_t)N * 8;                 // N*8 f
    unsigned short* wt = (unsigned short*)(adst + (size_t)N * 8);     // 272*128 bf16
    unsigned short* xh_bf = wt + 272 * 128;             // N*128 bf16
    int* cntn   = (int*)(xh_bf + (size_t)N * 128);      // N
    int* rowptr = cntn + N;                             // N
    int* esrc   = rowptr + N;                           // E+16 (padded)
    int* fill   = esrc + E + 16;                        // 256
    unsigned* binned = (unsigned*)(fill + 256);         // nb*BCAP u32

    k0_wt<<<136, 256, 0, stream>>>(lin_w, skip_w, att_src, att_dst, wt, esrc + E);

    k1f<<<nbin + G, 512, 0, stream>>>(
        x, wt, gat_bias, skip_b, ei, xh_bf, asrc, adst, out,
        fill, binned, N, E, nbin, ntiles, G);

    f3<<<nb, 256, 0, stream>>>(binned, fill, rowptr, cntn, esrc, N, nb);

    k3_agg<<<(N + 3) / 4, 256, 0, stream>>>(rowptr, cntn, esrc, asrc, adst,
                                            (const uint2*)xh_bf, out, N);
}

// Round 16
// 170.595 us; speedup vs baseline: 1.0173x; 1.0173x over previous
//
#include <hip/hip_runtime.h>
#include <math.h>

#define NEG 0.2f
#define BCAP 10240            // per-bucket slab capacity (mean 8163, +23 sigma)

typedef __attribute__((ext_vector_type(8))) short bf16x8;
typedef __attribute__((ext_vector_type(4))) float f32x4;

__device__ __forceinline__ unsigned short f2bf(float f) {
    unsigned u = __float_as_uint(f);
    u += 0x7fffu + ((u >> 16) & 1u);
    return (unsigned short)(u >> 16);
}
__device__ __forceinline__ unsigned pkbf(float a, float b) {
    return (unsigned)f2bf(a) | ((unsigned)f2bf(b) << 16);
}
__device__ __forceinline__ float blo(unsigned v) { return __uint_as_float(v << 16); }
__device__ __forceinline__ float bhi(unsigned v) { return __uint_as_float(v & 0xffff0000u); }
__device__ __forceinline__ float lrexp(float v) {
    v = v > 0.f ? v : NEG * v;
    return __expf(v);
}

// ---------------------------------------------------------------------------
// K0: build wt [272][128] bf16 transposed weights (lin | skip | w_as | w_ad)
// + zero the small scratch (esrc pad + fill).
// ---------------------------------------------------------------------------
__global__ __launch_bounds__(256) void k0_wt(
    const float* __restrict__ lin_w, const float* __restrict__ skip_w,
    const float* __restrict__ att_src, const float* __restrict__ att_dst,
    unsigned short* __restrict__ wt, int* __restrict__ zbase)
{
    int idx = blockIdx.x * 256 + threadIdx.x;   // 0..34815
    if (blockIdx.x == 0) {
        for (int z = threadIdx.x; z < 280; z += 256) zbase[z] = 0;
    }
    int c = idx >> 7, k = idx & 127;
    float v;
    if (c < 128) {
        v = lin_w[k * 128 + c];
    } else if (c < 256) {
        v = skip_w[k * 128 + (c - 128)];
    } else {
        int hh = c & 7;
        const float* att = (c & 8) ? att_dst : att_src;
        const float* wrow = lin_w + k * 128 + hh * 16;
        float s = 0.f;
#pragma unroll
        for (int j = 0; j < 16; ++j) s += wrow[j] * att[hh * 16 + j];
        v = s;
    }
    wt[c * 128 + k] = f2bf(v);
}

// ---------------------------------------------------------------------------
// K1F: [blocks 0..nbin) = edge binning; [nbin..) = persistent B-stationary
// MFMA GEMM (unchanged from R14).
// ---------------------------------------------------------------------------
__global__ __launch_bounds__(512, 2) void k1f(
    const float* __restrict__ x, const unsigned short* __restrict__ wt,
    const float* __restrict__ gat_bias, const float* __restrict__ skip_b,
    const int* __restrict__ ei,
    unsigned short* __restrict__ xh_bf, float* __restrict__ a_src,
    float* __restrict__ a_dst, float* __restrict__ out,
    int* __restrict__ fill, unsigned* __restrict__ binned,
    int nrows, int E, int nbin, int ntiles, int G)
{
    __shared__ int s1[256];
    __shared__ int s2[256];
    const int t = threadIdx.x;
    const int bid = blockIdx.x;

    if (bid < nbin) {                 // ---- binning role ----
        if (t < 256) s1[t] = 0;
        __syncthreads();
        int eb = bid * 8192;
        int srcv[16], dstv[16], rkv[16];
#pragma unroll
        for (int u = 0; u < 16; ++u) {
            int e = eb + u * 512 + t;
            srcv[u] = 0; dstv[u] = -1; rkv[u] = 0;
            if (e < E) {
                srcv[u] = ei[e];
                dstv[u] = ei[E + e];
                rkv[u] = atomicAdd(&s1[dstv[u] >> 9], 1);
            }
        }
        __syncthreads();
        if (t < 256) {
            int hc = s1[t];
            s2[t] = t * BCAP + (hc ? atomicAdd(&fill[t], hc) : 0);
        }
        __syncthreads();
#pragma unroll
        for (int u = 0; u < 16; ++u) {
            if (dstv[u] >= 0) {
                int b = dstv[u] >> 9;
                binned[s2[b] + rkv[u]] =
                    ((unsigned)(dstv[u] & 511) << 17) | (unsigned)srcv[u];
            }
        }
        return;
    }

    // ---- persistent GEMM role, B-stationary ----
    const int w = t >> 6, l = t & 63, r = l & 15, half = l >> 4;
    const int cb = w >> 2;

    bf16x8 Bf[4][8];                 // [ks][cf]
#pragma unroll
    for (int ks = 0; ks < 4; ++ks)
#pragma unroll
        for (int cf = 0; cf < 8; ++cf) {
            const int c = cb * 128 + cf * 16 + r;
            Bf[ks][cf] = *(const bf16x8*)(wt + c * 128 + ks * 32 + half * 8);
        }
    bf16x8 bA[4];
    float4 gb[8];
    if (cb == 0) {
#pragma unroll
        for (int ks = 0; ks < 4; ++ks)
            bA[ks] = *(const bf16x8*)(wt + (256 + r) * 128 + ks * 32 + half * 8);
    } else {
#pragma unroll
        for (int cf = 0; cf < 8; ++cf) {
            const int c0 = cf * 16 + half * 4;
            float4 g = *(const float4*)(gat_bias + c0);
            float4 sb = *(const float4*)(skip_b + c0);
            gb[cf] = make_float4(g.x + sb.x, g.y + sb.y, g.z + sb.z, g.w + sb.w);
        }
    }

    for (int tile = (bid - nbin); tile < ntiles; tile += G) {
        const int row0 = tile * 64 + (w & 3) * 16;
        const int row = row0 + r;
        const bool rowok = row < nrows;
        const float* xrow = x + (size_t)row * 128;

        bf16x8 aF[4];
#pragma unroll
        for (int ks = 0; ks < 4; ++ks) {
            float4 v0 = make_float4(0.f, 0.f, 0.f, 0.f), v1 = v0;
            if (rowok) {
                const float* gp = xrow + ks * 32 + half * 8;
                v0 = *(const float4*)gp;
                v1 = *(const float4*)(gp + 4);
            }
            bf16x8 a;
            a[0] = f2bf(v0.x); a[1] = f2bf(v0.y); a[2] = f2bf(v0.z); a[3] = f2bf(v0.w);
            a[4] = f2bf(v1.x); a[5] = f2bf(v1.y); a[6] = f2bf(v1.z); a[7] = f2bf(v1.w);
            aF[ks] = a;
        }

        f32x4 acc[8];
#pragma unroll
        for (int cf = 0; cf < 8; ++cf) acc[cf] = (f32x4){0.f, 0.f, 0.f, 0.f};
        f32x4 accA = (f32x4){0.f, 0.f, 0.f, 0.f};

#pragma unroll
        for (int ks = 0; ks < 4; ++ks) {
#pragma unroll
            for (int cf = 0; cf < 8; ++cf)
                acc[cf] = __builtin_amdgcn_mfma_f32_16x16x32_bf16(Bf[ks][cf], aF[ks], acc[cf], 0, 0, 0);
            if (cb == 0)
                accA = __builtin_amdgcn_mfma_f32_16x16x32_bf16(bA[ks], aF[ks], accA, 0, 0, 0);
        }

        if (rowok) {
            if (cb == 0) {
#pragma unroll
                for (int cf = 0; cf < 8; ++cf) {
                    uint2 pk;
                    pk.x = pkbf(acc[cf][0], acc[cf][1]);
                    pk.y = pkbf(acc[cf][2], acc[cf][3]);
                    *(uint2*)(xh_bf + (size_t)row * 128 + cf * 16 + half * 4) = pk;
                }
                float* adst_base = (half < 2) ? a_src : a_dst;
                *(float4*)(adst_base + (size_t)row * 8 + (half & 1) * 4) =
                    make_float4(accA[0], accA[1], accA[2], accA[3]);
            } else {
#pragma unroll
                for (int cf = 0; cf < 8; ++cf) {
                    const int c0 = cf * 16 + half * 4;
                    *(float4*)(out + (size_t)row * 128 + c0) =
                        make_float4(acc[cf][0] + gb[cf].x, acc[cf][1] + gb[cf].y,
                                    acc[cf][2] + gb[cf].z, acc[cf][3] + gb[cf].w);
                }
            }
        }
    }
}

// ---------------------------------------------------------------------------
// F3: one block per bucket (512 nodes). Single pass CSR build (unchanged).
// ---------------------------------------------------------------------------
__global__ __launch_bounds__(256) void f3(
    const unsigned* __restrict__ binned, const int* __restrict__ fill,
    int* __restrict__ rowptr, int* __restrict__ cntn,
    int* __restrict__ esrc, int N, int nb)
{
    __shared__ unsigned le[BCAP];    // 40 KB
    __shared__ int bs[256];
    __shared__ int h[512];
    __shared__ int sc[256];
    const int t = threadIdx.x;
    const int b = blockIdx.x;

    int c = (t < nb) ? fill[t] : 0;
    bs[t] = c;
    __syncthreads();
    for (int off = 1; off < 256; off <<= 1) {
        int a = (t >= off) ? bs[t - off] : 0;
        __syncthreads();
        bs[t] += a;
        __syncthreads();
    }
    const int cnt = fill[b];
    const int baseE = bs[b] - cnt;

    h[t] = 0; h[t + 256] = 0;
    __syncthreads();
    for (int e = t; e < cnt; e += 256) {
        unsigned p = binned[b * BCAP + e];
        le[e] = p;
        atomicAdd(&h[p >> 17], 1);
    }
    __syncthreads();
    int i0 = 2 * t, i1 = i0 + 1;
    int c0 = h[i0], c1 = h[i1], pv = c0 + c1;
    sc[t] = pv;
    __syncthreads();
    for (int off = 1; off < 256; off <<= 1) {
        int a = (t >= off) ? sc[t - off] : 0;
        __syncthreads();
        sc[t] += a;
        __syncthreads();
    }
    int ex = sc[t] - pv;
    int n0 = b * 512 + i0;
    if (n0 < N)     { rowptr[n0]     = baseE + ex;      cntn[n0]     = c0; }
    if (n0 + 1 < N) { rowptr[n0 + 1] = baseE + ex + c0; cntn[n0 + 1] = c1; }
    h[i0] = baseE + ex;
    h[i1] = baseE + ex + c0;
    __syncthreads();
    for (int e = t; e < cnt; e += 256) {
        unsigned p = le[e];
        int slot = atomicAdd(&h[p >> 17], 1);
        esrc[slot] = (int)(p & 0x1FFFFu);
    }
}

// ---------------------------------------------------------------------------
// K3 R16: R14 lane mapping (dword gathers, broadcast sb|q shuffles — 0 bank
// conflicts) with 16-edge chunks: producers compute pm0 (edges k..k+7) and
// pm1 (edges k+8..k+15); 16 gathers in flight per wave. Math identical.
// ---------------------------------------------------------------------------
__global__ __launch_bounds__(256) void k3_agg(
    const int* __restrict__ rowptr, const int* __restrict__ cntn,
    const int* __restrict__ esrc,
    const float* __restrict__ a_src, const float* __restrict__ a_dst,
    const unsigned int* __restrict__ xh32, float* __restrict__ out, int n)
{
    int i = blockIdx.x * 4 + (threadIdx.x >> 6);
    if (i >= n) return;
    const int lane = threadIdx.x & 63;
    const int h = lane >> 3, u = lane & 7;

    float adi = a_dst[(unsigned)i * 8 + h];
    float p0 = lrexp(a_src[(unsigned)i * 8 + h] + adi);
    unsigned uu = xh32[(unsigned)i * 64 + lane];
    float accx = p0 * blo(uu), accy = p0 * bhi(uu), den = p0;

    const int kbeg = rowptr[i], kend = kbeg + cntn[i];
    const int kl = kend - 1;
    for (int k = kbeg; k < kend; k += 16) {
        int ke0 = k + u, ke1 = k + 8 + u;
        int jm0 = esrc[min(ke0, kl)];
        int jm1 = esrc[min(ke1, kl)];
        float pm0 = (ke0 < kend) ? lrexp(a_src[(unsigned)jm0 * 8 + h] + adi) : 0.f;
        float pm1 = (ke1 < kend) ? lrexp(a_src[(unsigned)jm1 * 8 + h] + adi) : 0.f;

        int j0 = esrc[min(k + 0, kl)],  j1 = esrc[min(k + 1, kl)];
        int j2 = esrc[min(k + 2, kl)],  j3 = esrc[min(k + 3, kl)];
        int j4 = esrc[min(k + 4, kl)],  j5 = esrc[min(k + 5, kl)];
        int j6 = esrc[min(k + 6, kl)],  j7 = esrc[min(k + 7, kl)];
        int j8 = esrc[min(k + 8, kl)],  j9 = esrc[min(k + 9, kl)];
        int jA = esrc[min(k + 10, kl)], jB = esrc[min(k + 11, kl)];
        int jC = esrc[min(k + 12, kl)], jD = esrc[min(k + 13, kl)];
        int jE = esrc[min(k + 14, kl)], jF = esrc[min(k + 15, kl)];
        unsigned g0 = xh32[(unsigned)j0 * 64 + lane];
        unsigned g1 = xh32[(unsigned)j1 * 64 + lane];
        unsigned g2 = xh32[(unsigned)j2 * 64 + lane];
        unsigned g3 = xh32[(unsigned)j3 * 64 + lane];
        unsigned g4 = xh32[(unsigned)j4 * 64 + lane];
        unsigned g5 = xh32[(unsigned)j5 * 64 + lane];
        unsigned g6 = xh32[(unsigned)j6 * 64 + lane];
        unsigned g7 = xh32[(unsigned)j7 * 64 + lane];
        unsigned g8 = xh32[(unsigned)j8 * 64 + lane];
        unsigned g9 = xh32[(unsigned)j9 * 64 + lane];
        unsigned gA = xh32[(unsigned)jA * 64 + lane];
        unsigned gB = xh32[(unsigned)jB * 64 + lane];
        unsigned gC = xh32[(unsigned)jC * 64 + lane];
        unsigned gD = xh32[(unsigned)jD * 64 + lane];
        unsigned gE = xh32[(unsigned)jE * 64 + lane];
        unsigned gF = xh32[(unsigned)jF * 64 + lane];

        int sb = lane & 56;
        float p;
        p = __shfl(pm0, sb | 0, 64); accx += p * blo(g0); accy += p * bhi(g0); den += p;
        p = __shfl(pm0, sb | 1, 64); accx += p * blo(g1); accy += p * bhi(g1); den += p;
        p = __shfl(pm0, sb | 2, 64); accx += p * blo(g2); accy += p * bhi(g2); den += p;
        p = __shfl(pm0, sb | 3, 64); accx += p * blo(g3); accy += p * bhi(g3); den += p;
        p = __shfl(pm0, sb | 4, 64); accx += p * blo(g4); accy += p * bhi(g4); den += p;
        p = __shfl(pm0, sb | 5, 64); accx += p * blo(g5); accy += p * bhi(g5); den += p;
        p = __shfl(pm0, sb | 6, 64); accx += p * blo(g6); accy += p * bhi(g6); den += p;
        p = __shfl(pm0, sb | 7, 64); accx += p * blo(g7); accy += p * bhi(g7); den += p;
        p = __shfl(pm1, sb | 0, 64); accx += p * blo(g8); accy += p * bhi(g8); den += p;
        p = __shfl(pm1, sb | 1, 64); accx += p * blo(g9); accy += p * bhi(g9); den += p;
        p = __shfl(pm1, sb | 2, 64); accx += p * blo(gA); accy += p * bhi(gA); den += p;
        p = __shfl(pm1, sb | 3, 64); accx += p * blo(gB); accy += p * bhi(gB); den += p;
        p = __shfl(pm1, sb | 4, 64); accx += p * blo(gC); accy += p * bhi(gC); den += p;
        p = __shfl(pm1, sb | 5, 64); accx += p * blo(gD); accy += p * bhi(gD); den += p;
        p = __shfl(pm1, sb | 6, 64); accx += p * blo(gE); accy += p * bhi(gE); den += p;
        p = __shfl(pm1, sb | 7, 64); accx += p * blo(gF); accy += p * bhi(gF); den += p;
    }

    float inv = 1.f / (den + 1e-16f);
    unsigned o = (unsigned)i * 128 + lane * 2;
    float o0 = out[o]     + accx * inv;
    float o1 = out[o + 1] + accy * inv;
    o0 = o0 > 0.f ? o0 : __expf(o0) - 1.f;
    o1 = o1 > 0.f ? o1 : __expf(o1) - 1.f;
    out[o]     = o0;
    out[o + 1] = o1;
}

extern "C" void kernel_launch(void* const* d_in, const int* in_sizes, int n_in,
                              void* d_out, int out_size, void* d_ws, size_t ws_size,
                              hipStream_t stream)
{
    const float* x        = (const float*)d_in[0];
    const int*   ei       = (const int*)d_in[1];
    const float* lin_w    = (const float*)d_in[2];
    const float* att_src  = (const float*)d_in[3];
    const float* att_dst  = (const float*)d_in[4];
    const float* gat_bias = (const float*)d_in[5];
    const float* skip_w   = (const float*)d_in[6];
    const float* skip_b   = (const float*)d_in[7];
    float* out = (float*)d_out;

    const int N = in_sizes[0] / 128;
    const int E = in_sizes[1] / 2;
    const int nb   = (N + 511) >> 9;           // buckets (196)
    const int nbin = (E + 8191) / 8192;        // bin blocks (196)
    const int ntiles = (N + 63) / 64;
    int G = 2 * 256 - nbin;
    if (G < 64) G = 64;
    if (G > ntiles) G = ntiles;

    float* ws   = (float*)d_ws;
    float* asrc = ws;                                   // N*8 f
    float* adst = asrc + (size_t)N * 8;                 // N*8 f
    unsigned short* wt = (unsigned short*)(adst + (size_t)N * 8);     // 272*128 bf16
    unsigned short* xh_bf = wt + 272 * 128;             // N*128 bf16
    int* cntn   = (int*)(xh_bf + (size_t)N * 128);      // N
    int* rowptr = cntn + N;                             // N
    int* esrc   = rowptr + N;                           // E+16 (padded)
    int* fill   = esrc + E + 16;                        // 256
    unsigned* binned = (unsigned*)(fill + 256);         // nb*BCAP u32

    k0_wt<<<136, 256, 0, stream>>>(lin_w, skip_w, att_src, att_dst, wt, esrc + E);

    k1f<<<nbin + G, 512, 0, stream>>>(
        x, wt, gat_bias, skip_b, ei, xh_bf, asrc, adst, out,
        fill, binned, N, E, nbin, ntiles, G);

    f3<<<nb, 256, 0, stream>>>(binned, fill, rowptr, cntn, esrc, N, nb);

    k3_agg<<<(N + 3) / 4, 256, 0, stream>>>(rowptr, cntn, esrc, asrc, adst,
                                            (const unsigned int*)xh_bf, out, N);
}

// Round 17
// 169.244 us; speedup vs baseline: 1.0254x; 1.0080x over previous
//
#include <hip/hip_runtime.h>
#include <math.h>

#define NEG 0.2f
#define BCAP 10240            // per-bucket slab capacity (mean 8163, +23 sigma)

typedef __attribute__((ext_vector_type(8))) short bf16x8;
typedef __attribute__((ext_vector_type(4))) float f32x4;

__device__ __forceinline__ unsigned short f2bf(float f) {
    unsigned u = __float_as_uint(f);
    u += 0x7fffu + ((u >> 16) & 1u);
    return (unsigned short)(u >> 16);
}
__device__ __forceinline__ unsigned pkbf(float a, float b) {
    return (unsigned)f2bf(a) | ((unsigned)f2bf(b) << 16);
}
__device__ __forceinline__ float blo(unsigned v) { return __uint_as_float(v << 16); }
__device__ __forceinline__ float bhi(unsigned v) { return __uint_as_float(v & 0xffff0000u); }
__device__ __forceinline__ float lrexp(float v) {
    v = v > 0.f ? v : NEG * v;
    return __expf(v);
}

// ---------------------------------------------------------------------------
// K0: build wt [272][128] bf16 transposed weights (lin | skip | w_as | w_ad)
// + zero the small scratch (esrc pad + fill).
// ---------------------------------------------------------------------------
__global__ __launch_bounds__(256) void k0_wt(
    const float* __restrict__ lin_w, const float* __restrict__ skip_w,
    const float* __restrict__ att_src, const float* __restrict__ att_dst,
    unsigned short* __restrict__ wt, int* __restrict__ zbase)
{
    int idx = blockIdx.x * 256 + threadIdx.x;   // 0..34815
    if (blockIdx.x == 0) {
        for (int z = threadIdx.x; z < 280; z += 256) zbase[z] = 0;
    }
    int c = idx >> 7, k = idx & 127;
    float v;
    if (c < 128) {
        v = lin_w[k * 128 + c];
    } else if (c < 256) {
        v = skip_w[k * 128 + (c - 128)];
    } else {
        int hh = c & 7;
        const float* att = (c & 8) ? att_dst : att_src;
        const float* wrow = lin_w + k * 128 + hh * 16;
        float s = 0.f;
#pragma unroll
        for (int j = 0; j < 16; ++j) s += wrow[j] * att[hh * 16 + j];
        v = s;
    }
    wt[c * 128 + k] = f2bf(v);
}

// ---------------------------------------------------------------------------
// K1F: [blocks 0..nbin) = edge binning; [nbin..) = persistent B-stationary
// MFMA GEMM (unchanged from R14).
// ---------------------------------------------------------------------------
__global__ __launch_bounds__(512, 2) void k1f(
    const float* __restrict__ x, const unsigned short* __restrict__ wt,
    const float* __restrict__ gat_bias, const float* __restrict__ skip_b,
    const int* __restrict__ ei,
    unsigned short* __restrict__ xh_bf, float* __restrict__ a_src,
    float* __restrict__ a_dst, float* __restrict__ out,
    int* __restrict__ fill, unsigned* __restrict__ binned,
    int nrows, int E, int nbin, int ntiles, int G)
{
    __shared__ int s1[256];
    __shared__ int s2[256];
    const int t = threadIdx.x;
    const int bid = blockIdx.x;

    if (bid < nbin) {                 // ---- binning role ----
        if (t < 256) s1[t] = 0;
        __syncthreads();
        int eb = bid * 8192;
        int srcv[16], dstv[16], rkv[16];
#pragma unroll
        for (int u = 0; u < 16; ++u) {
            int e = eb + u * 512 + t;
            srcv[u] = 0; dstv[u] = -1; rkv[u] = 0;
            if (e < E) {
                srcv[u] = ei[e];
                dstv[u] = ei[E + e];
                rkv[u] = atomicAdd(&s1[dstv[u] >> 9], 1);
            }
        }
        __syncthreads();
        if (t < 256) {
            int hc = s1[t];
            s2[t] = t * BCAP + (hc ? atomicAdd(&fill[t], hc) : 0);
        }
        __syncthreads();
#pragma unroll
        for (int u = 0; u < 16; ++u) {
            if (dstv[u] >= 0) {
                int b = dstv[u] >> 9;
                binned[s2[b] + rkv[u]] =
                    ((unsigned)(dstv[u] & 511) << 17) | (unsigned)srcv[u];
            }
        }
        return;
    }

    // ---- persistent GEMM role, B-stationary ----
    const int w = t >> 6, l = t & 63, r = l & 15, half = l >> 4;
    const int cb = w >> 2;

    bf16x8 Bf[4][8];                 // [ks][cf]
#pragma unroll
    for (int ks = 0; ks < 4; ++ks)
#pragma unroll
        for (int cf = 0; cf < 8; ++cf) {
            const int c = cb * 128 + cf * 16 + r;
            Bf[ks][cf] = *(const bf16x8*)(wt + c * 128 + ks * 32 + half * 8);
        }
    bf16x8 bA[4];
    float4 gb[8];
    if (cb == 0) {
#pragma unroll
        for (int ks = 0; ks < 4; ++ks)
            bA[ks] = *(const bf16x8*)(wt + (256 + r) * 128 + ks * 32 + half * 8);
    } else {
#pragma unroll
        for (int cf = 0; cf < 8; ++cf) {
            const int c0 = cf * 16 + half * 4;
            float4 g = *(const float4*)(gat_bias + c0);
            float4 sb = *(const float4*)(skip_b + c0);
            gb[cf] = make_float4(g.x + sb.x, g.y + sb.y, g.z + sb.z, g.w + sb.w);
        }
    }

    for (int tile = (bid - nbin); tile < ntiles; tile += G) {
        const int row0 = tile * 64 + (w & 3) * 16;
        const int row = row0 + r;
        const bool rowok = row < nrows;
        const float* xrow = x + (size_t)row * 128;

        bf16x8 aF[4];
#pragma unroll
        for (int ks = 0; ks < 4; ++ks) {
            float4 v0 = make_float4(0.f, 0.f, 0.f, 0.f), v1 = v0;
            if (rowok) {
                const float* gp = xrow + ks * 32 + half * 8;
                v0 = *(const float4*)gp;
                v1 = *(const float4*)(gp + 4);
            }
            bf16x8 a;
            a[0] = f2bf(v0.x); a[1] = f2bf(v0.y); a[2] = f2bf(v0.z); a[3] = f2bf(v0.w);
            a[4] = f2bf(v1.x); a[5] = f2bf(v1.y); a[6] = f2bf(v1.z); a[7] = f2bf(v1.w);
            aF[ks] = a;
        }

        f32x4 acc[8];
#pragma unroll
        for (int cf = 0; cf < 8; ++cf) acc[cf] = (f32x4){0.f, 0.f, 0.f, 0.f};
        f32x4 accA = (f32x4){0.f, 0.f, 0.f, 0.f};

#pragma unroll
        for (int ks = 0; ks < 4; ++ks) {
#pragma unroll
            for (int cf = 0; cf < 8; ++cf)
                acc[cf] = __builtin_amdgcn_mfma_f32_16x16x32_bf16(Bf[ks][cf], aF[ks], acc[cf], 0, 0, 0);
            if (cb == 0)
                accA = __builtin_amdgcn_mfma_f32_16x16x32_bf16(bA[ks], aF[ks], accA, 0, 0, 0);
        }

        if (rowok) {
            if (cb == 0) {
#pragma unroll
                for (int cf = 0; cf < 8; ++cf) {
                    uint2 pk;
                    pk.x = pkbf(acc[cf][0], acc[cf][1]);
                    pk.y = pkbf(acc[cf][2], acc[cf][3]);
                    *(uint2*)(xh_bf + (size_t)row * 128 + cf * 16 + half * 4) = pk;
                }
                float* adst_base = (half < 2) ? a_src : a_dst;
                *(float4*)(adst_base + (size_t)row * 8 + (half & 1) * 4) =
                    make_float4(accA[0], accA[1], accA[2], accA[3]);
            } else {
#pragma unroll
                for (int cf = 0; cf < 8; ++cf) {
                    const int c0 = cf * 16 + half * 4;
                    *(float4*)(out + (size_t)row * 128 + c0) =
                        make_float4(acc[cf][0] + gb[cf].x, acc[cf][1] + gb[cf].y,
                                    acc[cf][2] + gb[cf].z, acc[cf][3] + gb[cf].w);
                }
            }
        }
    }
}

// ---------------------------------------------------------------------------
// F3: one block per bucket (512 nodes). Single pass CSR build (unchanged).
// ---------------------------------------------------------------------------
__global__ __launch_bounds__(256) void f3(
    const unsigned* __restrict__ binned, const int* __restrict__ fill,
    int* __restrict__ rowptr, int* __restrict__ cntn,
    int* __restrict__ esrc, int N, int nb)
{
    __shared__ unsigned le[BCAP];    // 40 KB
    __shared__ int bs[256];
    __shared__ int h[512];
    __shared__ int sc[256];
    const int t = threadIdx.x;
    const int b = blockIdx.x;

    int c = (t < nb) ? fill[t] : 0;
    bs[t] = c;
    __syncthreads();
    for (int off = 1; off < 256; off <<= 1) {
        int a = (t >= off) ? bs[t - off] : 0;
        __syncthreads();
        bs[t] += a;
        __syncthreads();
    }
    const int cnt = fill[b];
    const int baseE = bs[b] - cnt;

    h[t] = 0; h[t + 256] = 0;
    __syncthreads();
    for (int e = t; e < cnt; e += 256) {
        unsigned p = binned[b * BCAP + e];
        le[e] = p;
        atomicAdd(&h[p >> 17], 1);
    }
    __syncthreads();
    int i0 = 2 * t, i1 = i0 + 1;
    int c0 = h[i0], c1 = h[i1], pv = c0 + c1;
    sc[t] = pv;
    __syncthreads();
    for (int off = 1; off < 256; off <<= 1) {
        int a = (t >= off) ? sc[t - off] : 0;
        __syncthreads();
        sc[t] += a;
        __syncthreads();
    }
    int ex = sc[t] - pv;
    int n0 = b * 512 + i0;
    if (n0 < N)     { rowptr[n0]     = baseE + ex;      cntn[n0]     = c0; }
    if (n0 + 1 < N) { rowptr[n0 + 1] = baseE + ex + c0; cntn[n0 + 1] = c1; }
    h[i0] = baseE + ex;
    h[i1] = baseE + ex + c0;
    __syncthreads();
    for (int e = t; e < cnt; e += 256) {
        unsigned p = le[e];
        int slot = atomicAdd(&h[p >> 17], 1);
        esrc[slot] = (int)(p & 0x1FFFFu);
    }
}

// ---------------------------------------------------------------------------
// K3 (R14 form, best-measured 90 µs): 8-edge chunk, tail-clamped gathers,
// dword gathers, broadcast sb|q shuffles (0 bank conflicts).
// ---------------------------------------------------------------------------
__global__ __launch_bounds__(256) void k3_agg(
    const int* __restrict__ rowptr, const int* __restrict__ cntn,
    const int* __restrict__ esrc,
    const float* __restrict__ a_src, const float* __restrict__ a_dst,
    const unsigned int* __restrict__ xh32, float* __restrict__ out, int n)
{
    int i = blockIdx.x * 4 + (threadIdx.x >> 6);
    if (i >= n) return;
    const int lane = threadIdx.x & 63;
    const int h = lane >> 3, u = lane & 7;

    float adi = a_dst[(unsigned)i * 8 + h];
    float p0 = lrexp(a_src[(unsigned)i * 8 + h] + adi);
    unsigned uu = xh32[(unsigned)i * 64 + lane];
    float accx = p0 * blo(uu), accy = p0 * bhi(uu), den = p0;

    const int kbeg = rowptr[i], kend = kbeg + cntn[i];
    const int kl = kend - 1;
    for (int k = kbeg; k < kend; k += 8) {
        int ke = k + u;
        int jm = esrc[min(ke, kl)];
        float pmv = lrexp(a_src[(unsigned)jm * 8 + h] + adi);
        float pm = (ke < kend) ? pmv : 0.f;

        int j0 = esrc[min(k + 0, kl)], j1 = esrc[min(k + 1, kl)];
        int j2 = esrc[min(k + 2, kl)], j3 = esrc[min(k + 3, kl)];
        int j4 = esrc[min(k + 4, kl)], j5 = esrc[min(k + 5, kl)];
        int j6 = esrc[min(k + 6, kl)], j7 = esrc[min(k + 7, kl)];
        unsigned g0 = xh32[(unsigned)j0 * 64 + lane];
        unsigned g1 = xh32[(unsigned)j1 * 64 + lane];
        unsigned g2 = xh32[(unsigned)j2 * 64 + lane];
        unsigned g3 = xh32[(unsigned)j3 * 64 + lane];
        unsigned g4 = xh32[(unsigned)j4 * 64 + lane];
        unsigned g5 = xh32[(unsigned)j5 * 64 + lane];
        unsigned g6 = xh32[(unsigned)j6 * 64 + lane];
        unsigned g7 = xh32[(unsigned)j7 * 64 + lane];

        int sb = lane & 56;
        float p;
        p = __shfl(pm, sb | 0, 64); accx += p * blo(g0); accy += p * bhi(g0); den += p;
        p = __shfl(pm, sb | 1, 64); accx += p * blo(g1); accy += p * bhi(g1); den += p;
        p = __shfl(pm, sb | 2, 64); accx += p * blo(g2); accy += p * bhi(g2); den += p;
        p = __shfl(pm, sb | 3, 64); accx += p * blo(g3); accy += p * bhi(g3); den += p;
        p = __shfl(pm, sb | 4, 64); accx += p * blo(g4); accy += p * bhi(g4); den += p;
        p = __shfl(pm, sb | 5, 64); accx += p * blo(g5); accy += p * bhi(g5); den += p;
        p = __shfl(pm, sb | 6, 64); accx += p * blo(g6); accy += p * bhi(g6); den += p;
        p = __shfl(pm, sb | 7, 64); accx += p * blo(g7); accy += p * bhi(g7); den += p;
    }

    float inv = 1.f / (den + 1e-16f);
    unsigned o = (unsigned)i * 128 + lane * 2;
    float o0 = out[o]     + accx * inv;
    float o1 = out[o + 1] + accy * inv;
    o0 = o0 > 0.f ? o0 : __expf(o0) - 1.f;
    o1 = o1 > 0.f ? o1 : __expf(o1) - 1.f;
    out[o]     = o0;
    out[o + 1] = o1;
}

extern "C" void kernel_launch(void* const* d_in, const int* in_sizes, int n_in,
                              void* d_out, int out_size, void* d_ws, size_t ws_size,
                              hipStream_t stream)
{
    const float* x        = (const float*)d_in[0];
    const int*   ei       = (const int*)d_in[1];
    const float* lin_w    = (const float*)d_in[2];
    const float* att_src  = (const float*)d_in[3];
    const float* att_dst  = (const float*)d_in[4];
    const float* gat_bias = (const float*)d_in[5];
    const float* skip_w   = (const float*)d_in[6];
    const float* skip_b   = (const float*)d_in[7];
    float* out = (float*)d_out;

    const int N = in_sizes[0] / 128;
    const int E = in_sizes[1] / 2;
    const int nb   = (N + 511) >> 9;           // buckets (196)
    const int nbin = (E + 8191) / 8192;        // bin blocks (196)
    const int ntiles = (N + 63) / 64;
    int G = 2 * 256 - nbin;
    if (G < 64) G = 64;
    if (G > ntiles) G = ntiles;

    float* ws   = (float*)d_ws;
    float* asrc = ws;                                   // N*8 f
    float* adst = asrc + (size_t)N * 8;                 // N*8 f
    unsigned short* wt = (unsigned short*)(adst + (size_t)N * 8);     // 272*128 bf16
    unsigned short* xh_bf = wt + 272 * 128;             // N*128 bf16
    int* cntn   = (int*)(xh_bf + (size_t)N * 128);      // N
    int* rowptr = cntn + N;                             // N
    int* esrc   = rowptr + N;                           // E+16 (padded)
    int* fill   = esrc + E + 16;                        // 256
    unsigned* binned = (unsigned*)(fill + 256);         // nb*BCAP u32

    k0_wt<<<136, 256, 0, stream>>>(lin_w, skip_w, att_src, att_dst, wt, esrc + E);

    k1f<<<nbin + G, 512, 0, stream>>>(
        x, wt, gat_bias, skip_b, ei, xh_bf, asrc, adst, out,
        fill, binned, N, E, nbin, ntiles, G);

    f3<<<nb, 256, 0, stream>>>(binned, fill, rowptr, cntn, esrc, N, nb);

    k3_agg<<<(N + 3) / 4, 256, 0, stream>>>(rowptr, cntn, esrc, asrc, adst,
                                            (const unsigned int*)xh_bf, out, N);
}